// Round 2
// baseline (539.901 us; speedup 1.0000x reference)
//
#include <hip/hip_runtime.h>
#include <hip/hip_cooperative_groups.h>

namespace cg = cooperative_groups;

#define BS   8
#define NCH  7
#define PX   409600      // 640*640
#define NBIN 65536
#define NCHK 256
#define WIN_LO 0x3000u   // LDS histogram window over top-16 bits: [0x3000, 0x4000)
#define WIN_SZ 4096
#define EPSF 1e-6f
#define NT   256

__device__ __forceinline__ float sigf(float x) {
    return 1.0f / (1.0f + __expf(-x));
}

__device__ __forceinline__ unsigned wred_u(unsigned v) {
    #pragma unroll
    for (int o = 32; o; o >>= 1) v += __shfl_down(v, o);
    return v;
}

__device__ __forceinline__ float wred_f(float v) {
    #pragma unroll
    for (int o = 32; o; o >>= 1) v += __shfl_down(v, o);
    return v;
}

// =====================================================================================
// two-level coalesced select: chunks[256] (chunk c = bins [c*256,(c+1)*256)), bins[65536]
// finds bin s.t. count(elements in bins >= bin) >= k, strictly < k above; rank in bin.
// =====================================================================================
__device__ void select2(const unsigned* __restrict__ chunks,
                        const unsigned* __restrict__ bins,
                        unsigned k, unsigned* out_bin, unsigned* out_rank) {
    __shared__ unsigned cs[256];
    __shared__ unsigned sel_c, sel_r;
    int t = threadIdx.x;
    cs[t] = chunks[t];                 // coalesced
    __syncthreads();
    #pragma unroll
    for (int off = 1; off < 256; off <<= 1) {
        unsigned v = cs[t];
        unsigned a = (t + off < 256) ? cs[t + off] : 0u;
        __syncthreads();
        cs[t] = v + a;
        __syncthreads();
    }
    {
        unsigned sfx  = cs[t];
        unsigned sfx1 = (t < 255) ? cs[t + 1] : 0u;
        if (sfx >= k && sfx1 < k) { sel_c = (unsigned)t; sel_r = k - sfx1; }
    }
    __syncthreads();
    unsigned chunk = sel_c, krem = sel_r;
    cs[t] = bins[chunk * 256 + t];     // coalesced
    __syncthreads();
    #pragma unroll
    for (int off = 1; off < 256; off <<= 1) {
        unsigned v = cs[t];
        unsigned a = (t + off < 256) ? cs[t + off] : 0u;
        __syncthreads();
        cs[t] = v + a;
        __syncthreads();
    }
    {
        unsigned sfx  = cs[t];
        unsigned sfx1 = (t < 255) ? cs[t + 1] : 0u;
        if (sfx >= krem && sfx1 < krem) {
            *out_bin  = chunk * 256 + (unsigned)t;
            *out_rank = krem - sfx1;
        }
    }
    __syncthreads();
}

// =====================================================================================
// Fully fused cooperative kernel: P0 zero -> P1 main pass -> P2 select-hi ->
// P3 refine -> P4 select-lo -> P5 L_c sums -> P6 final.  One dispatch total.
// __launch_bounds__(256,4): 4 waves/EU target -> 128-VGPR budget so the 14-load
// cluster in P1 can stay in flight (round-1's implicit 64-VGPR target sank it).
// =====================================================================================
__global__ __launch_bounds__(256, 4) void k_fused(
        const float* __restrict__ preds, const int* __restrict__ labels,
        const int* __restrict__ mask,
        unsigned* __restrict__ hist1, unsigned* __restrict__ hist2,
        unsigned* __restrict__ chunks1, unsigned* __restrict__ chunks2,
        unsigned* __restrict__ n_pos, unsigned* __restrict__ hi_bin,
        unsigned* __restrict__ rankv, unsigned* __restrict__ activev,
        float* __restrict__ thr, float* __restrict__ sums,
        float* __restrict__ out) {
    cg::grid_group grid = cg::this_grid();
    const int tid = threadIdx.x;
    const unsigned nblk = gridDim.x;
    const unsigned nthr = nblk * NT;
    const unsigned gtid = blockIdx.x * NT + tid;
    const unsigned bpb  = nblk >> 3;          // blocks per batch (nblk % 8 == 0)

    __shared__ unsigned lh[WIN_SZ];
    __shared__ unsigned csum[256];
    __shared__ unsigned ws2[2][4];
    __shared__ float    red[4][18];

    // ---------------- P0: zero the contiguous workspace ----------------------------
    {
        const size_t zw = (size_t)2 * BS * NBIN + (size_t)2 * BS * NCHK
                        + 5 * BS + (size_t)BS * 21;
        for (size_t i = gtid; i < zw; i += nthr) hist1[i] = 0u;
    }
    for (int j = tid; j < WIN_SZ; j += NT) lh[j] = 0u;
    grid.sync();

    // ---------------- P1: histogram + n_pos + 18 L_s sums ---------------------------
    {
        const unsigned b  = blockIdx.x / bpb;
        const unsigned cb = blockIdx.x % bpb;
        const float* pr = preds + (size_t)b * NCH * PX;
        const int*   lb = labels + (size_t)b * NCH * PX;
        const int*   mk = mask + (size_t)b * PX;

        unsigned pos_cnt = 0, zero_cnt = 0;
        float acc[18];
        #pragma unroll
        for (int j = 0; j < 18; j++) acc[j] = 0.f;

        for (unsigned g = cb * NT + tid; g < PX / 4; g += bpb * NT) {
            int px = (int)g * 4;
            // ---- issue ALL 14 dwordx4 loads first ----
            float4 p6 = *(const float4*)(pr + 6 * PX + px);
            int4   m4 = *(const int4*)(mk + px);
            float4 pc[6];
            int4   lc[6];
            #pragma unroll
            for (int c = 0; c < 6; c++) pc[c] = *(const float4*)(pr + c * PX + px);
            #pragma unroll
            for (int c = 0; c < 6; c++) lc[c] = *(const int4*)(lb + c * PX + px);

            // ---- histogram / W from p6+mask (overlaps channel-load latency) ----
            float mm[4]  = {(float)m4.x, (float)m4.y, (float)m4.z, (float)m4.w};
            float p6a[4] = {p6.x, p6.y, p6.z, p6.w};
            float W[4];
            #pragma unroll
            for (int u = 0; u < 4; u++) {
                float pn = sigf(p6a[u]) * mm[u];
                if (pn >= 0.5f) {
                    pos_cnt++; W[u] = 1.0f;
                } else {
                    W[u] = 0.0f;
                    unsigned bits = __float_as_uint(pn);
                    if (bits == 0u) {
                        zero_cnt++;
                    } else {
                        unsigned hb = bits >> 16;
                        if (hb - WIN_LO < WIN_SZ) {
                            atomicAdd(&lh[hb - WIN_LO], 1u);
                        } else {   // rare fallback
                            atomicAdd(&hist1[(size_t)b * NBIN + hb], 1u);
                            atomicAdd(&chunks1[b * NCHK + (hb >> 8)], 1u);
                        }
                    }
                }
            }

            // ---- the 18 thr-independent L_s sums ----
            #pragma unroll
            for (int c = 0; c < 6; c++) {
                float pcs[4] = {pc[c].x, pc[c].y, pc[c].z, pc[c].w};
                float lcs[4] = {(float)lc[c].x, (float)lc[c].y,
                                (float)lc[c].z, (float)lc[c].w};
                #pragma unroll
                for (int u = 0; u < 4; u++) {
                    float s = sigf(pcs[u]);
                    float l = lcs[u];
                    acc[c]      += s * l * W[u];   // sn[c]
                    acc[6 + c]  += s * s * W[u];   // sp[c]
                    acc[12 + c] += l * W[u];       // sl[c]
                }
            }
        }
        __syncthreads();

        // flush LDS window histogram to global bins (coalesced) ...
        for (int j = tid; j < WIN_SZ; j += NT) {
            unsigned c = lh[j];
            if (c) atomicAdd(&hist1[(size_t)b * NBIN + WIN_LO + j], c);
        }
        // ... and the 16 window chunk sums (chunks 48..63)
        {
            unsigned s = 0;
            int chunk = tid >> 4, part = tid & 15;
            const unsigned* base = &lh[chunk * 256 + part * 16];
            #pragma unroll
            for (int j = 0; j < 16; j++) s += base[j];
            csum[tid] = s;
        }
        __syncthreads();
        if (tid < 16) {
            unsigned s = 0;
            #pragma unroll
            for (int j = 0; j < 16; j++) s += csum[tid * 16 + j];
            if (s) atomicAdd(&chunks1[b * NCHK + 48 + tid], s);
        }

        // block-reduce pos/zero counts
        unsigned pv = wred_u(pos_cnt), zv = wred_u(zero_cnt);
        int lane = tid & 63, wid = tid >> 6;
        if (lane == 0) { ws2[0][wid] = pv; ws2[1][wid] = zv; }
        __syncthreads();
        if (tid == 0) {
            unsigned pt = 0, zt = 0;
            #pragma unroll
            for (int w = 0; w < 4; w++) { pt += ws2[0][w]; zt += ws2[1][w]; }
            if (pt) atomicAdd(&n_pos[b], pt);
            if (zt) {
                atomicAdd(&hist1[(size_t)b * NBIN], zt);
                atomicAdd(&chunks1[b * NCHK], zt);
            }
        }

        // block-reduce the 18 L_s sums into sums[b][3..20]
        #pragma unroll
        for (int j = 0; j < 18; j++) {
            float v = wred_f(acc[j]);
            if (lane == 0) red[wid][j] = v;
        }
        __syncthreads();
        if (tid < 18) {
            float tot = red[0][tid] + red[1][tid] + red[2][tid] + red[3][tid];
            atomicAdd(&sums[b * 21 + 3 + tid], tot);
        }
    }
    grid.sync();

    // ---------------- P2: select top-16-bit bin (blocks 0..7) -----------------------
    if (blockIdx.x < BS) {
        int b = blockIdx.x;
        unsigned np_ = n_pos[b];
        unsigned k = np_ * 3u;
        unsigned nneg = (unsigned)PX - np_;
        if (!(nneg > k && k > 0u)) {
            if (tid == 0) { activev[b] = 0u; thr[b] = -1.0f; }  // M = 1 everywhere
        } else {
            __shared__ unsigned rb, rr;
            select2(chunks1 + b * NCHK, hist1 + (size_t)b * NBIN, k, &rb, &rr);
            if (tid == 0) {
                activev[b] = 1u;
                hi_bin[b] = rb;
                rankv[b] = rr;
                // bin 0: pn==0 pixels contribute 0 to every L_c sum under any M
                if (rb == 0u) thr[b] = 0.0f;
            }
        }
    }
    grid.sync();

    // ---------------- P3: refine low-16-bit histogram within selected hi bin --------
    for (int b3 = 0; b3 < BS; b3++) {
        if (!activev[b3]) continue;
        unsigned hi = hi_bin[b3];
        if (hi == 0u) continue;
        const float* pr = preds + ((size_t)b3 * NCH + 6) * PX;
        const int*   mk = mask + (size_t)b3 * PX;
        unsigned* h2 = hist2 + (size_t)b3 * NBIN;
        unsigned* c2 = chunks2 + b3 * NCHK;
        for (unsigned g = gtid; g < PX / 4; g += nthr) {
            int px = (int)g * 4;
            float4 p6 = *(const float4*)(pr + px);
            int4   m4 = *(const int4*)(mk + px);
            float p6a[4] = {p6.x, p6.y, p6.z, p6.w};
            float mm[4]  = {(float)m4.x, (float)m4.y, (float)m4.z, (float)m4.w};
            #pragma unroll
            for (int u = 0; u < 4; u++) {
                float pn = sigf(p6a[u]) * mm[u];
                if (pn < 0.5f) {
                    unsigned bits = __float_as_uint(pn);
                    if ((bits >> 16) == hi) {
                        unsigned lo = bits & 0xFFFFu;
                        atomicAdd(&h2[lo], 1u);
                        atomicAdd(&c2[lo >> 8], 1u);
                    }
                }
            }
        }
    }
    grid.sync();

    // ---------------- P4: resolve exact threshold bits (blocks 0..7) ----------------
    if (blockIdx.x < BS) {
        int b = blockIdx.x;
        if (activev[b] && hi_bin[b] != 0u) {
            __shared__ unsigned rb2, rr2;
            select2(chunks2 + b * NCHK, hist2 + (size_t)b * NBIN, rankv[b], &rb2, &rr2);
            if (tid == 0) thr[b] = __uint_as_float((hi_bin[b] << 16) | rb2);
        }
    }
    grid.sync();

    // ---------------- P5: the 3 thr-dependent L_c sums ------------------------------
    {
        const unsigned b  = blockIdx.x / bpb;
        const unsigned cb = blockIdx.x % bpb;
        const float* pr = preds + ((size_t)b * NCH + 6) * PX;
        const int*   lb = labels + ((size_t)b * NCH + 6) * PX;
        const int*   mk = mask + (size_t)b * PX;
        float thr_b = thr[b];

        float a0 = 0.f, a1 = 0.f, a2 = 0.f;
        for (unsigned g = cb * NT + tid; g < PX / 4; g += bpb * NT) {
            int px = (int)g * 4;
            float4 p6 = *(const float4*)(pr + px);
            int4   l4 = *(const int4*)(lb + px);
            int4   m4 = *(const int4*)(mk + px);
            float p6a[4] = {p6.x, p6.y, p6.z, p6.w};
            float la[4]  = {(float)l4.x, (float)l4.y, (float)l4.z, (float)l4.w};
            float mm[4]  = {(float)m4.x, (float)m4.y, (float)m4.z, (float)m4.w};
            #pragma unroll
            for (int u = 0; u < 4; u++) {
                float pn = sigf(p6a[u]) * mm[u];
                float Mi = (pn >= thr_b) ? 1.0f : 0.0f;
                float ln = la[u] * mm[u];
                a0 += pn * ln * Mi;
                a1 += pn * pn * Mi;
                a2 += ln * Mi;
            }
        }
        int lane = tid & 63, wid = tid >> 6;
        float v0 = wred_f(a0), v1 = wred_f(a1), v2 = wred_f(a2);
        __syncthreads();                 // red[] reuse safety
        if (lane == 0) { red[wid][0] = v0; red[wid][1] = v1; red[wid][2] = v2; }
        __syncthreads();
        if (tid < 3) {
            float tot = red[0][tid] + red[1][tid] + red[2][tid] + red[3][tid];
            atomicAdd(&sums[b * 21 + tid], tot);
        }
    }
    grid.sync();

    // ---------------- P6: final dice + means (block 0) ------------------------------
    if (blockIdx.x == 0) {
        int t = tid;
        float Lc = 0.f, Ls = 0.f;
        if (t < BS) {
            const float* s = sums + t * 21;
            Lc = 1.0f - (2.0f * s[0]) / (s[1] + s[2] + EPSF);
            float a = 0.f;
            #pragma unroll
            for (int c = 0; c < 6; c++)
                a += (2.0f * s[3 + c]) / (s[9 + c] + s[15 + c] + EPSF);
            Ls = 1.0f - a * (1.0f / 6.0f);
        }
        #pragma unroll
        for (int o = 4; o; o >>= 1) { Lc += __shfl_down(Lc, o); Ls += __shfl_down(Ls, o); }
        if (t == 0) {
            float lc_m = Lc * (1.0f / (float)BS);
            float ls_m = Ls * (1.0f / (float)BS);
            out[0] = lc_m;
            out[1] = ls_m;
            out[2] = 0.7f * lc_m + 0.3f * ls_m;
        }
    }
}

extern "C" void kernel_launch(void* const* d_in, const int* in_sizes, int n_in,
                              void* d_out, int out_size, void* d_ws, size_t ws_size,
                              hipStream_t stream) {
    const float* preds = (const float*)d_in[0];
    const int* labels  = (const int*)d_in[1];
    const int* mask    = (const int*)d_in[2];
    float* out = (float*)d_out;

    // workspace layout (u32/f32 words) — contiguous so P0 can zero linearly
    unsigned* hist1   = (unsigned*)d_ws;              // BS * NBIN
    unsigned* hist2   = hist1 + (size_t)BS * NBIN;    // BS * NBIN
    unsigned* chunks1 = hist2 + (size_t)BS * NBIN;    // BS * NCHK
    unsigned* chunks2 = chunks1 + (size_t)BS * NCHK;  // BS * NCHK
    unsigned* n_pos   = chunks2 + (size_t)BS * NCHK;  // BS
    unsigned* hi_bin  = n_pos + BS;                   // BS
    unsigned* rankv   = hi_bin + BS;                  // BS
    unsigned* activev = rankv + BS;                   // BS
    float*    thr     = (float*)(activev + BS);       // BS
    float*    sums    = thr + BS;                     // BS * 21

    static int maxBlk = 0;
    if (maxBlk == 0) {
        hipError_t e = hipOccupancyMaxActiveBlocksPerMultiprocessor(&maxBlk, k_fused, NT, 0);
        if (e != hipSuccess || maxBlk < 1) maxBlk = 1;
    }
    int nblk = maxBlk * 256;          // 256 CUs on MI355X
    if (nblk > 2048) nblk = 2048;
    nblk &= ~7;                       // multiple of 8 (batch mapping)
    if (nblk < 8) nblk = 8;

    void* args[] = { (void*)&preds, (void*)&labels, (void*)&mask,
                     (void*)&hist1, (void*)&hist2, (void*)&chunks1, (void*)&chunks2,
                     (void*)&n_pos, (void*)&hi_bin, (void*)&rankv, (void*)&activev,
                     (void*)&thr, (void*)&sums, (void*)&out };
    hipLaunchCooperativeKernel((void*)k_fused, dim3(nblk), dim3(NT), args, 0, stream);
}